// Round 10
// baseline (17.301 us; speedup 1.0000x reference)
//
#include <hip/hip_runtime.h>
#include <math.h>

#define SR_I 16000
#define FRAMES 500
#define UP 64
#define AUDIO (FRAMES * UP)
#define POLY 8
#define HARM 64
#define NYQ 8000.0f

// -------------------------------------------------------------------------
// Single fused kernel, TWO frames per block: block g handles frames
// t0=2g, t1=2g+1 of batch b; 8 waves; wave p = voice p; lane k owns output
// sample (t,k).  Identical math to the passing R9 kernel; the only change:
// the 4 scattered c-gathers (64 cache lines EACH -> 256 lane-address TA
// transactions per wave) are replaced by ONE aligned global_load_dwordx4
// per lane (+ a second only when the uniform frame-window misaligns) and a
// wave-uniform component remap.  c[k, t0-1..t0+2] is contiguous in the
// [harm][frames] row; row bases are 16B-aligned (500 % 4 == 0).
// Boundary blocks (t0==0, t0==498) remap components to reproduce the clamp
// exactly; all off0==0 cases skip the second load (no OOB past the
// page-exact c buffer).
//
// Phase math (exact f64):
//   P[t] = (64*S_t + 8*(x[t]-x[t-1]))/SR,  S_t = sum_{j<t} x[j]
//   in-frame inclusive scan, closed form (increments linear in lane k):
//     lanes 0..31 : S(k) = [(k+1)A + (B-A)(k(k+1)/2 + 32.5(k+1))/64]/SR
//     lanes 32..63: q=k-32, S = (8A+24B)/SR + [(q+1)B + (C-B)(q+1)^2/128]/SR
// Anti-alias mask baked into LDS quads at staging; harmonic loop is
// ds_read_b128(bcast) + 3 fma + fract + v_sin + fma, 4x unrolled.
// -------------------------------------------------------------------------
__global__ __launch_bounds__(512) void k_fused(const float* __restrict__ f0,
                                               const float* __restrict__ cc,
                                               const float* __restrict__ vv,
                                               const float* __restrict__ rp,
                                               float* __restrict__ out) {
    __shared__ float4 quads[2][POLY][2][HARM];   // 32 KiB: [frame][voice][half][lane]
    __shared__ float part[2][POLY][UP];          //  4 KiB

    const int blk = blockIdx.x;            // 0 .. 2*(FRAMES/2)-1
    const int b = blk / (FRAMES / 2);
    const int g = blk - b * (FRAMES / 2);
    const int t0 = 2 * g;
    const int t1 = t0 + 1;
    const int tid = threadIdx.x;
    const int p = tid >> 6;                // wave index = voice
    const int k = tid & 63;
    const bool lowhalf = (k < 32);

    const int tm = max(t0 - 1, 0);          // frame t0-1 (clamped)
    const int tq = min(t0 + 2, FRAMES - 1); // frame t0+2 (clamped)

    const int bpi = b * POLY + p;
    const float* f0p = f0 + bpi * FRAMES;
    const float* vp  = vv + bpi * FRAMES;
    const float* cp  = cc + (size_t)bpi * HARM * FRAMES;

    // ---- c[k, t0-1..t0+2] via 1-2 aligned dwordx4 + uniform remap ----
    const int base_t = min(max(t0 - 1, 0), FRAMES - 4);  // window start
    const int off0 = base_t & 3;                          // uniform 0..3
    const int Wb = base_t - off0;                         // 16B-aligned start
    const float* crow = cp + (size_t)k * FRAMES + Wb;
    const float4 q0 = *reinterpret_cast<const float4*>(crow);
    float4 q1 = q0;
    if (off0 != 0)                                        // uniform branch
        q1 = *reinterpret_cast<const float4*>(crow + 4);  // in-row, aligned

    float cm, cb, cx, cd;   // c[k] at frames (tm, t0, t1, tq)
    if (t0 == 0)            { cm = q0.x; cb = q0.x; cx = q0.y; cd = q0.z; }
    else if (t0 == 498)     { cm = q0.y; cb = q0.z; cx = q0.w; cd = q0.w; }
    else if (off0 == 0)     { cm = q0.x; cb = q0.y; cx = q0.z; cd = q0.w; }
    else if (off0 == 1)     { cm = q0.y; cb = q0.z; cx = q0.w; cd = q1.x; }
    else if (off0 == 2)     { cm = q0.z; cb = q0.w; cx = q1.x; cd = q1.y; }
    else                    { cm = q0.w; cb = q1.x; cx = q1.y; cd = q1.z; }

    const float rpl = rp[bpi * HARM + k];

    float pre[8];                             // predicated prefix loads (j < t0)
    #pragma unroll
    for (int u = 0; u < 8; ++u) {
        const int j = k + u * 64;
        pre[u] = (j < t0) ? f0p[j] : 0.0f;
    }

    const float A = f0p[tm];
    const float B = f0p[t0];
    const float C = f0p[t1];
    const float D = f0p[tq];
    const float vA = vp[tm];
    const float vB = vp[t0];
    const float vC = vp[t1];
    const float vD = vp[tq];

    // ---- masks (per source frame) and pre-masked quads for both frames ----
    const float nf = (float)(k + 1);
    const bool mA = (nf * A < NYQ);
    const bool mB = (nf * B < NYQ);
    const bool mC = (nf * C < NYQ);
    const bool mD = (nf * D < NYQ);
    const float qA = mA ? cm : 0.0f;
    const float qB = mB ? cb : 0.0f;
    const float qC = mC ? cx : 0.0f;
    const float qD = mD ? cd : 0.0f;
    // frame0 interp sources: low (t0-1, t0), high (t0, t1)
    quads[0][p][0][k] = make_float4(qA, qB, rpl, 0.0f);
    quads[0][p][1][k] = make_float4(qB, qC, rpl, 0.0f);
    // frame1 interp sources: low (t0, t1), high (t1, t0+2)
    quads[1][p][0][k] = make_float4(qB, qC, rpl, 0.0f);
    quads[1][p][1][k] = make_float4(qC, qD, rpl, 0.0f);

    // wave-uniform harmonic caps (mask monotone in n)
    int hm0 = (int)__popcll(__ballot(mA || mB || mC));
    int hm1 = (int)__popcll(__ballot(mB || mC || mD));
    hm0 = (hm0 + 3) & ~3;
    hm1 = (hm1 + 3) & ~3;

    // ---- frame prefix sums (f64): one reduction serves both frames ----
    double ssum = 0.0;
    #pragma unroll
    for (int u = 0; u < 8; ++u) ssum += (double)pre[u];
    #pragma unroll
    for (int off = 32; off; off >>= 1)
        ssum += __shfl_xor(ssum, off, 64);
    const double dA = (double)A, dB = (double)B, dC = (double)C, dD = (double)D;
    const double Pfr0 = (64.0 * ssum + 8.0 * (dB - dA)) * (1.0 / (double)SR_I);
    const double Pfr1 = (64.0 * (ssum + dB) + 8.0 * (dC - dB)) * (1.0 / (double)SR_I);

    // ---- in-frame inclusive scans, closed form ----
    const double kk = (double)k;
    const double qq = (double)(k - 32);
    double S0, S1;
    if (lowhalf) {
        const double lin = (kk * (kk + 1.0) * 0.5 + 32.5 * (kk + 1.0)) * (1.0 / 64.0);
        S0 = ((kk + 1.0) * dA + (dB - dA) * lin) * (1.0 / (double)SR_I);
        S1 = ((kk + 1.0) * dB + (dC - dB) * lin) * (1.0 / (double)SR_I);
    } else {
        const double sq = (qq + 1.0) * (qq + 1.0) * (1.0 / 128.0);
        S0 = (8.0 * dA + 24.0 * dB + (qq + 1.0) * dB + (dC - dB) * sq) * (1.0 / (double)SR_I);
        S1 = (8.0 * dB + 24.0 * dC + (qq + 1.0) * dC + (dD - dC) * sq) * (1.0 / (double)SR_I);
    }
    const double Phi0 = Pfr0 + S0;
    const double Phi1 = Pfr1 + S1;
    const float phi0 = (float)(Phi0 - floor(Phi0));
    const float phi1 = (float)(Phi1 - floor(Phi1));

    // per-lane interpolation weights and v envelopes
    const float w = (lowhalf ? ((float)k + 32.5f) : ((float)k - 31.5f)) * (1.0f / 64.0f);
    const float w1 = 1.0f - w;
    const float v00 = lowhalf ? vA : vB;   // frame0 sources
    const float v01 = lowhalf ? vB : vC;
    const float v10 = lowhalf ? vB : vC;   // frame1 sources
    const float v11 = lowhalf ? vC : vD;
    const float vu0 = 0.04f * (w1 * v00 + w * v01);
    const float vu1 = 0.04f * (w1 * v10 + w * v11);

    const int half = lowhalf ? 0 : 1;

    // ---- harmonic loops (frame0 then frame1), 4x unrolled ----
    #pragma unroll
    for (int f = 0; f < 2; ++f) {
        const int hmax = f ? hm1 : hm0;
        const float phi = f ? phi1 : phi0;
        const float W0 = (f ? vu1 : vu0) * w1;
        const float W1 = (f ? vu1 : vu0) * w;
        const float4* qb = &quads[f][p][half][0];

        float acc0 = 0.0f, acc1 = 0.0f, acc2 = 0.0f, acc3 = 0.0f;
        float nf0 = 1.0f, nf1 = 2.0f, nf2 = 3.0f, nf3 = 4.0f;

        for (int n0 = 1; n0 <= hmax; n0 += 4) {
            const float4 qa = qb[n0 - 1];
            const float4 qc = qb[n0 + 0];
            const float4 qd = qb[n0 + 1];
            const float4 qe = qb[n0 + 2];
            {
                const float cup = fmaf(W1, qa.y, W0 * qa.x);
                const float ph  = fmaf(nf0, phi, qa.z);
                acc0 = fmaf(cup, __builtin_amdgcn_sinf(__builtin_amdgcn_fractf(ph)), acc0);
            }
            {
                const float cup = fmaf(W1, qc.y, W0 * qc.x);
                const float ph  = fmaf(nf1, phi, qc.z);
                acc1 = fmaf(cup, __builtin_amdgcn_sinf(__builtin_amdgcn_fractf(ph)), acc1);
            }
            {
                const float cup = fmaf(W1, qd.y, W0 * qd.x);
                const float ph  = fmaf(nf2, phi, qd.z);
                acc2 = fmaf(cup, __builtin_amdgcn_sinf(__builtin_amdgcn_fractf(ph)), acc2);
            }
            {
                const float cup = fmaf(W1, qe.y, W0 * qe.x);
                const float ph  = fmaf(nf3, phi, qe.z);
                acc3 = fmaf(cup, __builtin_amdgcn_sinf(__builtin_amdgcn_fractf(ph)), acc3);
            }
            nf0 += 4.0f; nf1 += 4.0f; nf2 += 4.0f; nf3 += 4.0f;
        }
        part[f][p][k] = (acc0 + acc1) + (acc2 + acc3);
    }

    __syncthreads();
    if (tid < 128) {
        const int f = tid >> 6;
        const int j = tid & 63;
        float sum = 0.0f;
        #pragma unroll
        for (int q = 0; q < POLY; ++q) sum += part[f][q][j];
        out[(size_t)b * AUDIO + (t0 + f) * UP + j] = sum;
    }
}

extern "C" void kernel_launch(void* const* d_in, const int* in_sizes, int n_in,
                              void* d_out, int out_size, void* d_ws, size_t ws_size,
                              hipStream_t stream) {
    const float* f0 = (const float*)d_in[0];   // (2,8,500)
    const float* c  = (const float*)d_in[1];   // (2,8,64,500)
    const float* v  = (const float*)d_in[2];   // (2,8,500)
    // d_in[3] = a (loudness) — unused by the output
    const float* rp = (const float*)d_in[4];   // (2,512,1)
    float* out = (float*)d_out;                // (2,32000)

    k_fused<<<2 * (FRAMES / 2), 512, 0, stream>>>(f0, c, v, rp, out);
}